// Round 1
// baseline (1989.426 us; speedup 1.0000x reference)
//
#include <hip/hip_runtime.h>
#include <math.h>

#define EMB 1024
#define TSEQ 2048
#define NBATCH 4
#define NHEAD 16
#define HDIM 64
#define MROWS (NBATCH * TSEQ) /* 8192 */

// ---------------------------------------------------------------------------
// NT GEMM body: C[m][n] = sum_k A[m][k] * B[n][k]
// A: (M x 1024) row-major, B: (N x 1024) row-major, C: (M x 1024-width) rows.
// Tile 128x128x32, 256 threads, 8x8 micro-tile per thread.
// LDS tiles stored k-major (transposed) so compute reads are float4 on the
// m/n axis: A-side reads broadcast across 16 lanes, B-side ~4-way (BW-bound).
// ---------------------------------------------------------------------------
__device__ __forceinline__ void gemm_nt_body(const float* __restrict__ A,
                                             const float* __restrict__ B,
                                             float* __restrict__ C,
                                             int bm, int bn) {
  __shared__ __align__(16) float As[32][128];
  __shared__ __align__(16) float Bs[32][128];
  const int tid = threadIdx.x;
  const int tx = tid & 15;
  const int ty = tid >> 4;
  const int sr = tid >> 2;        // staging row 0..63 (16 distinct rows/wave/instr -> 4-way store)
  const int sc = (tid & 3) << 3;  // staging col base 0,8,16,24

  float acc[8][8];
#pragma unroll
  for (int i = 0; i < 8; ++i)
#pragma unroll
    for (int j = 0; j < 8; ++j) acc[i][j] = 0.f;

  for (int k0 = 0; k0 < EMB; k0 += 32) {
    // stage A,B tiles (128 rows x 32 k) transposed into LDS
#pragma unroll
    for (int jj = 0; jj < 2; ++jj) {
      const int r = sr + (jj << 6);
      const float* Arow = A + (size_t)(bm + r) * EMB + k0 + sc;
      const float* Brow = B + (size_t)(bn + r) * EMB + k0 + sc;
#pragma unroll
      for (int u = 0; u < 2; ++u) {
        const float4 av = *(const float4*)(Arow + (u << 2));
        const float4 bv = *(const float4*)(Brow + (u << 2));
        const int c = sc + (u << 2);
        As[c + 0][r] = av.x; As[c + 1][r] = av.y;
        As[c + 2][r] = av.z; As[c + 3][r] = av.w;
        Bs[c + 0][r] = bv.x; Bs[c + 1][r] = bv.y;
        Bs[c + 2][r] = bv.z; Bs[c + 3][r] = bv.w;
      }
    }
    __syncthreads();
#pragma unroll 4
    for (int kk = 0; kk < 32; ++kk) {
      const float4 a0 = *(const float4*)&As[kk][(ty << 3) + 0];
      const float4 a1 = *(const float4*)&As[kk][(ty << 3) + 4];
      const float4 b0 = *(const float4*)&Bs[kk][(tx << 3) + 0];
      const float4 b1 = *(const float4*)&Bs[kk][(tx << 3) + 4];
      const float a[8] = {a0.x, a0.y, a0.z, a0.w, a1.x, a1.y, a1.z, a1.w};
      const float b[8] = {b0.x, b0.y, b0.z, b0.w, b1.x, b1.y, b1.z, b1.w};
#pragma unroll
      for (int i = 0; i < 8; ++i)
#pragma unroll
        for (int j = 0; j < 8; ++j)
          acc[i][j] = fmaf(a[i], b[j], acc[i][j]);
    }
    __syncthreads();
  }
#pragma unroll
  for (int i = 0; i < 8; ++i) {
    float* Crow = C + (size_t)(bm + (ty << 3) + i) * EMB + bn + (tx << 3);
    const float4 c0 = make_float4(acc[i][0], acc[i][1], acc[i][2], acc[i][3]);
    const float4 c1 = make_float4(acc[i][4], acc[i][5], acc[i][6], acc[i][7]);
    *(float4*)(Crow + 0) = c0;
    *(float4*)(Crow + 4) = c1;
  }
}

// Fused QKV: grid (64, 24); blockIdx.y selects which weight/output.
__global__ __launch_bounds__(256, 2) void gemm_qkv_kernel(
    const float* __restrict__ x,
    const float* __restrict__ Wk, const float* __restrict__ Wq,
    const float* __restrict__ Wv,
    float* __restrict__ kbuf, float* __restrict__ qbuf, float* __restrict__ vbuf) {
  const int sel = blockIdx.y >> 3;
  const float* B = (sel == 0) ? Wk : (sel == 1) ? Wq : Wv;
  float* C = (sel == 0) ? kbuf : (sel == 1) ? qbuf : vbuf;
  gemm_nt_body(x, B, C, blockIdx.x * 128, (blockIdx.y & 7) * 128);
}

__global__ __launch_bounds__(256, 2) void gemm_out_kernel(
    const float* __restrict__ A, const float* __restrict__ Wu,
    float* __restrict__ C) {
  gemm_nt_body(A, Wu, C, blockIdx.x * 128, blockIdx.y * 128);
}

// ---------------------------------------------------------------------------
// Per-head LayerNorm on q and k, in place. One 64-lane wave per 64-elem group.
// ---------------------------------------------------------------------------
__global__ __launch_bounds__(256) void ln_kernel(
    float* __restrict__ qbuf, float* __restrict__ kbuf,
    const float* __restrict__ qw, const float* __restrict__ qb,
    const float* __restrict__ kw, const float* __restrict__ kb) {
  const int NG = MROWS * NHEAD;  // 131072 groups per tensor
  const int wid = (int)((blockIdx.x * blockDim.x + threadIdx.x) >> 6);
  const int lane = threadIdx.x & 63;
  float* base;
  const float* w;
  const float* bia;
  if (wid < NG) {
    base = qbuf + (size_t)wid * HDIM; w = qw; bia = qb;
  } else {
    base = kbuf + (size_t)(wid - NG) * HDIM; w = kw; bia = kb;
  }
  const float xv = base[lane];
  float s = xv;
#pragma unroll
  for (int m = 32; m >= 1; m >>= 1) s += __shfl_xor(s, m, 64);
  const float mu = s * (1.f / 64.f);
  const float d = xv - mu;
  float vs = d * d;
#pragma unroll
  for (int m = 32; m >= 1; m >>= 1) vs += __shfl_xor(vs, m, 64);
  const float inv = rsqrtf(vs * (1.f / 64.f) + 1e-5f);
  base[lane] = d * inv * w[lane] + bia[lane];
}

// ---------------------------------------------------------------------------
// Causal flash attention, fp32. Grid (T/64, b*h). Block 256 = 16x16 threads.
// 64x64 Q tile; iterate k-tiles 0..qt; online softmax in registers; row stats
// reduced over the 16 lanes owning each row via shfl_xor. LDS = 64 KB exactly.
// q,k,v,o layout: (b, t, h, s) flat, row stride EMB.
// ---------------------------------------------------------------------------
__global__ __launch_bounds__(256, 2) void attn_kernel(
    const float* __restrict__ Qg, const float* __restrict__ Kg,
    const float* __restrict__ Vg, float* __restrict__ Og) {
  __shared__ __align__(16) float Qs[64][64];  // [d][r] transposed
  __shared__ __align__(16) float Ks[64][64];  // [d][c] transposed
  __shared__ __align__(16) float Vs[64][64];  // [c][d] natural
  __shared__ __align__(16) float Ps[64][64];  // [c][r] transposed, XOR-swizzled
  const int tid = threadIdx.x;
  const int tx = tid & 15;
  const int ty = tid >> 4;
  const int qt = blockIdx.x;
  const int bh = blockIdx.y;
  const int bb = bh >> 4;
  const int hh = bh & 15;
  const int q0 = qt << 6;
  const size_t base = ((size_t)bb * TSEQ) * EMB + hh * HDIM;
  const float* Qp = Qg + base;
  const float* Kp = Kg + base;
  const float* Vp = Vg + base;
  float* Op = Og + base;

  const int sr = tid >> 2;        // 0..63
  const int sc = (tid & 3) << 4;  // 0,16,32,48

  // stage Q tile transposed
#pragma unroll
  for (int i = 0; i < 4; ++i) {
    const int c = sc + (i << 2);
    const float4 qv = *(const float4*)(Qp + (size_t)(q0 + sr) * EMB + c);
    Qs[c + 0][sr] = qv.x; Qs[c + 1][sr] = qv.y;
    Qs[c + 2][sr] = qv.z; Qs[c + 3][sr] = qv.w;
  }

  float o[4][4];
  float mrow[4], lrow[4];
#pragma unroll
  for (int i = 0; i < 4; ++i) {
    mrow[i] = -INFINITY;
    lrow[i] = 0.f;
#pragma unroll
    for (int j = 0; j < 4; ++j) o[i][j] = 0.f;
  }

  for (int t = 0; t <= qt; ++t) {
    const int k0 = t << 6;
    // stage K (transposed) and V (natural)
#pragma unroll
    for (int i = 0; i < 4; ++i) {
      const int c = sc + (i << 2);
      const float4 kv = *(const float4*)(Kp + (size_t)(k0 + sr) * EMB + c);
      Ks[c + 0][sr] = kv.x; Ks[c + 1][sr] = kv.y;
      Ks[c + 2][sr] = kv.z; Ks[c + 3][sr] = kv.w;
      const float4 vv = *(const float4*)(Vp + (size_t)(k0 + sr) * EMB + c);
      *(float4*)&Vs[sr][c] = vv;
    }
    __syncthreads();

    // S = Q K^T for this tile: rows ty*4.., cols tx*4..
    float s[4][4];
#pragma unroll
    for (int i = 0; i < 4; ++i)
#pragma unroll
      for (int j = 0; j < 4; ++j) s[i][j] = 0.f;

#pragma unroll 8
    for (int d = 0; d < 64; ++d) {
      const float4 qa = *(const float4*)&Qs[d][ty << 2];
      const float4 ka = *(const float4*)&Ks[d][tx << 2];
      const float a4[4] = {qa.x, qa.y, qa.z, qa.w};
      const float b4[4] = {ka.x, ka.y, ka.z, ka.w};
#pragma unroll
      for (int i = 0; i < 4; ++i)
#pragma unroll
        for (int j = 0; j < 4; ++j)
          s[i][j] = fmaf(a4[i], b4[j], s[i][j]);
    }

    const bool diag = (t == qt);
#pragma unroll
    for (int i = 0; i < 4; ++i) {
#pragma unroll
      for (int j = 0; j < 4; ++j) {
        s[i][j] *= 0.125f;  // 1/sqrt(64)
        if (diag && ((tx << 2) + j > (ty << 2) + i)) s[i][j] = -INFINITY;
      }
      float rm = fmaxf(fmaxf(s[i][0], s[i][1]), fmaxf(s[i][2], s[i][3]));
#pragma unroll
      for (int mm = 1; mm < 16; mm <<= 1) rm = fmaxf(rm, __shfl_xor(rm, mm, 64));
      const float mn = fmaxf(mrow[i], rm);
      const float corr = __expf(mrow[i] - mn);  // exp(-inf)=0 on first tile
      mrow[i] = mn;
      float rsum = 0.f;
#pragma unroll
      for (int j = 0; j < 4; ++j) {
        const float p = __expf(s[i][j] - mn);  // masked: exp(-inf)=0
        s[i][j] = p;
        rsum += p;
      }
#pragma unroll
      for (int mm = 1; mm < 16; mm <<= 1) rsum += __shfl_xor(rsum, mm, 64);
      lrow[i] = lrow[i] * corr + rsum;
#pragma unroll
      for (int j = 0; j < 4; ++j) o[i][j] *= corr;
      // write P transposed with XOR swizzle to break store conflicts
#pragma unroll
      for (int j = 0; j < 4; ++j) {
        const int cc = (tx << 2) + j;
        Ps[cc][((ty << 2) + i) ^ ((cc & 7) << 2)] = s[i][j];
      }
    }
    __syncthreads();

    // O += P * V
#pragma unroll 8
    for (int c = 0; c < 64; ++c) {
      const float4 pa = *(const float4*)&Ps[c][(ty << 2) ^ ((c & 7) << 2)];
      const float4 va = *(const float4*)&Vs[c][tx << 2];
      const float a4[4] = {pa.x, pa.y, pa.z, pa.w};
      const float b4[4] = {va.x, va.y, va.z, va.w};
#pragma unroll
      for (int i = 0; i < 4; ++i)
#pragma unroll
        for (int j = 0; j < 4; ++j)
          o[i][j] = fmaf(a4[i], b4[j], o[i][j]);
    }
    __syncthreads();
  }

#pragma unroll
  for (int i = 0; i < 4; ++i) {
    const float inv = 1.f / lrow[i];
    const float4 ov = make_float4(o[i][0] * inv, o[i][1] * inv,
                                  o[i][2] * inv, o[i][3] * inv);
    *(float4*)(Op + (size_t)(q0 + (ty << 2) + i) * EMB + (tx << 2)) = ov;
  }
}

// ---------------------------------------------------------------------------
extern "C" void kernel_launch(void* const* d_in, const int* in_sizes, int n_in,
                              void* d_out, int out_size, void* d_ws, size_t ws_size,
                              hipStream_t stream) {
  const float* x  = (const float*)d_in[0];
  const float* Wk = (const float*)d_in[1];
  const float* Wq = (const float*)d_in[2];
  const float* Wv = (const float*)d_in[3];
  const float* Wu = (const float*)d_in[4];
  const float* klnw = (const float*)d_in[5];
  const float* klnb = (const float*)d_in[6];
  const float* qlnw = (const float*)d_in[7];
  const float* qlnb = (const float*)d_in[8];
  float* out = (float*)d_out;

  float* ws = (float*)d_ws;
  const size_t tensor_elems = (size_t)MROWS * EMB;  // 8M floats each
  float* kbuf = ws;
  float* qbuf = ws + tensor_elems;
  float* vbuf = ws + 2 * tensor_elems;
  float* abuf = ws + 3 * tensor_elems;  // needs 128 MB of workspace total

  // 1) fused QKV projections: k,q,v = x @ W{k,q,v}^T
  gemm_qkv_kernel<<<dim3(MROWS / 128, 24), 256, 0, stream>>>(
      x, Wk, Wq, Wv, kbuf, qbuf, vbuf);

  // 2) per-head LayerNorm on q and k (in place)
  {
    const int total_waves = 2 * MROWS * NHEAD;   // 262144
    const int blocks = total_waves / 4;          // 4 waves per 256-thread block
    ln_kernel<<<blocks, 256, 0, stream>>>(qbuf, kbuf, qlnw, qlnb, klnw, klnb);
  }

  // 3) causal flash attention -> abuf in (b,t,h,s) layout
  attn_kernel<<<dim3(TSEQ / 64, NBATCH * NHEAD), 256, 0, stream>>>(
      qbuf, kbuf, vbuf, abuf);

  // 4) output projection: out = abuf @ Wu^T
  gemm_out_kernel<<<dim3(MROWS / 128, EMB / 128), 256, 0, stream>>>(
      abuf, Wu, out);
}

// Round 2
// 1065.262 us; speedup vs baseline: 1.8675x; 1.8675x over previous
//
#include <hip/hip_runtime.h>
#include <math.h>

#define EMB 1024
#define TSEQ 2048
#define NBATCH 4
#define NHEAD 16
#define HDIM 64
#define MROWS (NBATCH * TSEQ) /* 8192 */
#define KPAD 72  /* bf16 LDS row pitch: 36 words, 16B-aligned, bank-spreading */

typedef __attribute__((ext_vector_type(8))) short bf16x8;
typedef __attribute__((ext_vector_type(4))) float f32x4;
typedef __attribute__((ext_vector_type(8))) unsigned short u16x8;

__device__ __forceinline__ unsigned short f2bf(float f) {
  unsigned int x = __float_as_uint(f);
  unsigned int r = x + 0x7fffu + ((x >> 16) & 1u);
  return (unsigned short)(r >> 16);
}

// ---------------------------------------------------------------------------
// fp32 NT GEMM body (unchanged from R1): C[m][n] = sum_k A[m][k]*B[n][k]
// ---------------------------------------------------------------------------
__device__ __forceinline__ void gemm_nt_body(const float* __restrict__ A,
                                             const float* __restrict__ B,
                                             float* __restrict__ C,
                                             int bm, int bn) {
  __shared__ __align__(16) float As[32][128];
  __shared__ __align__(16) float Bs[32][128];
  const int tid = threadIdx.x;
  const int tx = tid & 15;
  const int ty = tid >> 4;
  const int sr = tid >> 2;
  const int sc = (tid & 3) << 3;

  float acc[8][8];
#pragma unroll
  for (int i = 0; i < 8; ++i)
#pragma unroll
    for (int j = 0; j < 8; ++j) acc[i][j] = 0.f;

  for (int k0 = 0; k0 < EMB; k0 += 32) {
#pragma unroll
    for (int jj = 0; jj < 2; ++jj) {
      const int r = sr + (jj << 6);
      const float* Arow = A + (size_t)(bm + r) * EMB + k0 + sc;
      const float* Brow = B + (size_t)(bn + r) * EMB + k0 + sc;
#pragma unroll
      for (int u = 0; u < 2; ++u) {
        const float4 av = *(const float4*)(Arow + (u << 2));
        const float4 bv = *(const float4*)(Brow + (u << 2));
        const int c = sc + (u << 2);
        As[c + 0][r] = av.x; As[c + 1][r] = av.y;
        As[c + 2][r] = av.z; As[c + 3][r] = av.w;
        Bs[c + 0][r] = bv.x; Bs[c + 1][r] = bv.y;
        Bs[c + 2][r] = bv.z; Bs[c + 3][r] = bv.w;
      }
    }
    __syncthreads();
#pragma unroll 4
    for (int kk = 0; kk < 32; ++kk) {
      const float4 a0 = *(const float4*)&As[kk][(ty << 3) + 0];
      const float4 a1 = *(const float4*)&As[kk][(ty << 3) + 4];
      const float4 b0 = *(const float4*)&Bs[kk][(tx << 3) + 0];
      const float4 b1 = *(const float4*)&Bs[kk][(tx << 3) + 4];
      const float a[8] = {a0.x, a0.y, a0.z, a0.w, a1.x, a1.y, a1.z, a1.w};
      const float b[8] = {b0.x, b0.y, b0.z, b0.w, b1.x, b1.y, b1.z, b1.w};
#pragma unroll
      for (int i = 0; i < 8; ++i)
#pragma unroll
        for (int j = 0; j < 8; ++j)
          acc[i][j] = fmaf(a[i], b[j], acc[i][j]);
    }
    __syncthreads();
  }
#pragma unroll
  for (int i = 0; i < 8; ++i) {
    float* Crow = C + (size_t)(bm + (ty << 3) + i) * EMB + bn + (tx << 3);
    *(float4*)(Crow + 0) = make_float4(acc[i][0], acc[i][1], acc[i][2], acc[i][3]);
    *(float4*)(Crow + 4) = make_float4(acc[i][4], acc[i][5], acc[i][6], acc[i][7]);
  }
}

// ---------------------------------------------------------------------------
// Fused QKV. sel 0->k fp32, 1->q fp32, 2->v written bf16 TRANSPOSED [b][h][d][t]
// ---------------------------------------------------------------------------
__global__ __launch_bounds__(256, 2) void gemm_qkv_kernel(
    const float* __restrict__ x,
    const float* __restrict__ Wk, const float* __restrict__ Wq,
    const float* __restrict__ Wv,
    float* __restrict__ kbuf, float* __restrict__ qbuf,
    unsigned short* __restrict__ vb16) {
  __shared__ __align__(16) float As[32][128];
  __shared__ __align__(16) float Bs[32][128];
  const int sel = blockIdx.y >> 3;
  const float* B = (sel == 0) ? Wk : (sel == 1) ? Wq : Wv;
  const int bm = blockIdx.x * 128;
  const int bn = (blockIdx.y & 7) * 128;
  const int tid = threadIdx.x;
  const int tx = tid & 15;
  const int ty = tid >> 4;
  const int sr = tid >> 2;
  const int sc = (tid & 3) << 3;

  float acc[8][8];
#pragma unroll
  for (int i = 0; i < 8; ++i)
#pragma unroll
    for (int j = 0; j < 8; ++j) acc[i][j] = 0.f;

  for (int k0 = 0; k0 < EMB; k0 += 32) {
#pragma unroll
    for (int jj = 0; jj < 2; ++jj) {
      const int r = sr + (jj << 6);
      const float* Arow = x + (size_t)(bm + r) * EMB + k0 + sc;
      const float* Brow = B + (size_t)(bn + r) * EMB + k0 + sc;
#pragma unroll
      for (int u = 0; u < 2; ++u) {
        const float4 av = *(const float4*)(Arow + (u << 2));
        const float4 bv = *(const float4*)(Brow + (u << 2));
        const int c = sc + (u << 2);
        As[c + 0][r] = av.x; As[c + 1][r] = av.y;
        As[c + 2][r] = av.z; As[c + 3][r] = av.w;
        Bs[c + 0][r] = bv.x; Bs[c + 1][r] = bv.y;
        Bs[c + 2][r] = bv.z; Bs[c + 3][r] = bv.w;
      }
    }
    __syncthreads();
#pragma unroll 4
    for (int kk = 0; kk < 32; ++kk) {
      const float4 a0 = *(const float4*)&As[kk][(ty << 3) + 0];
      const float4 a1 = *(const float4*)&As[kk][(ty << 3) + 4];
      const float4 b0 = *(const float4*)&Bs[kk][(tx << 3) + 0];
      const float4 b1 = *(const float4*)&Bs[kk][(tx << 3) + 4];
      const float a[8] = {a0.x, a0.y, a0.z, a0.w, a1.x, a1.y, a1.z, a1.w};
      const float b[8] = {b0.x, b0.y, b0.z, b0.w, b1.x, b1.y, b1.z, b1.w};
#pragma unroll
      for (int i = 0; i < 8; ++i)
#pragma unroll
        for (int j = 0; j < 8; ++j)
          acc[i][j] = fmaf(a[i], b[j], acc[i][j]);
    }
    __syncthreads();
  }

  if (sel < 2) {
    float* C = (sel == 0) ? kbuf : qbuf;
#pragma unroll
    for (int i = 0; i < 8; ++i) {
      float* Crow = C + (size_t)(bm + (ty << 3) + i) * EMB + bn + (tx << 3);
      *(float4*)(Crow + 0) = make_float4(acc[i][0], acc[i][1], acc[i][2], acc[i][3]);
      *(float4*)(Crow + 4) = make_float4(acc[i][4], acc[i][5], acc[i][6], acc[i][7]);
    }
  } else {
    // v: write bf16, transposed per head: vb16[((b*16+h)*64+d)*2048 + t]
    const int m0 = bm + (ty << 3);       // t-global (8-aligned)
    const int bb = m0 >> 11;
    const int tl = m0 & 2047;
    const int n0 = bn + (tx << 3);
#pragma unroll
    for (int j = 0; j < 8; ++j) {
      const int n = n0 + j;
      const int h = n >> 6;
      const int dd = n & 63;
      u16x8 v;
#pragma unroll
      for (int i = 0; i < 8; ++i) v[i] = f2bf(acc[i][j]);
      *(u16x8*)(vb16 + ((size_t)((bb << 4) + h) * 64 + dd) * TSEQ + tl) = v;
    }
  }
}

__global__ __launch_bounds__(256, 2) void gemm_out_kernel(
    const float* __restrict__ A, const float* __restrict__ Wu,
    float* __restrict__ C) {
  gemm_nt_body(A, Wu, C, blockIdx.x * 128, blockIdx.y * 128);
}

// ---------------------------------------------------------------------------
// Per-head LayerNorm on q,k: reads fp32, writes bf16 (same (t, h*64+d) layout)
// ---------------------------------------------------------------------------
__global__ __launch_bounds__(256) void ln_kernel(
    const float* __restrict__ qf, const float* __restrict__ kf,
    unsigned short* __restrict__ qo, unsigned short* __restrict__ ko,
    const float* __restrict__ qw, const float* __restrict__ qb,
    const float* __restrict__ kw, const float* __restrict__ kb) {
  const int NG = MROWS * NHEAD;
  const int wid = (int)((blockIdx.x * blockDim.x + threadIdx.x) >> 6);
  const int lane = threadIdx.x & 63;
  const float* src;
  unsigned short* dst;
  const float* w;
  const float* bia;
  if (wid < NG) {
    src = qf + (size_t)wid * HDIM; dst = qo + (size_t)wid * HDIM; w = qw; bia = qb;
  } else {
    src = kf + (size_t)(wid - NG) * HDIM; dst = ko + (size_t)(wid - NG) * HDIM; w = kw; bia = kb;
  }
  const float xv = src[lane];
  float s = xv;
#pragma unroll
  for (int m = 32; m >= 1; m >>= 1) s += __shfl_xor(s, m, 64);
  const float mu = s * (1.f / 64.f);
  const float d = xv - mu;
  float vs = d * d;
#pragma unroll
  for (int m = 32; m >= 1; m >>= 1) vs += __shfl_xor(vs, m, 64);
  const float inv = rsqrtf(vs * (1.f / 64.f) + 1e-5f);
  dst[lane] = f2bf(d * inv * w[lane] + bia[lane]);
}

// ---------------------------------------------------------------------------
// bf16-MFMA causal flash attention. Block 256 = 4 waves; 64 q rows per block
// (16 per wave); K/V tiles of 64. Swapped QK^T (mfma(K,Q) -> S^T) so softmax
// rows are lane-local (16 vals) + 2 shuffles. P via per-wave LDS (no barrier).
// Q,K from bf16 (t, h*64+d); V from bf16 transposed [b*h][d][t]. O fp32 (t,e).
// ---------------------------------------------------------------------------
__global__ __launch_bounds__(256, 2) void attn_kernel(
    const unsigned short* __restrict__ Qg, const unsigned short* __restrict__ Kg,
    const unsigned short* __restrict__ Vt, float* __restrict__ Og) {
  __shared__ __align__(16) unsigned short Ks[64][KPAD];
  __shared__ __align__(16) unsigned short Vs[64][KPAD];
  __shared__ __align__(16) unsigned short Ps[4][16][KPAD];
  const int tid = threadIdx.x;
  const int lane = tid & 63;
  const int w = tid >> 6;      // wave 0..3
  const int lq = lane & 15;    // operand row/col index
  const int g = lane >> 4;     // k-group 0..3
  const int qt = (int)(gridDim.x - 1 - blockIdx.x);  // big blocks first
  const int bh = blockIdx.y;
  const int bb = bh >> 4;
  const int hh = bh & 15;
  const int q0 = qt << 6;
  const unsigned short* Qb = Qg + ((size_t)bb * TSEQ) * EMB + hh * HDIM;
  const unsigned short* Kb = Kg + ((size_t)bb * TSEQ) * EMB + hh * HDIM;
  const unsigned short* Vb = Vt + (size_t)bh * HDIM * TSEQ;
  float* Ob = Og + ((size_t)bb * TSEQ) * EMB + hh * HDIM;

  // Q fragments (registers): row q0+16w+lq, d = 8g..8g+7 (+32)
  bf16x8 qf0, qf1;
  {
    const unsigned short* qp = Qb + (size_t)(q0 + (w << 4) + lq) * EMB + (g << 3);
    qf0 = *(const bf16x8*)(qp);
    qf1 = *(const bf16x8*)(qp + 32);
  }

  f32x4 o[4];
#pragma unroll
  for (int nb = 0; nb < 4; ++nb) o[nb] = (f32x4){0.f, 0.f, 0.f, 0.f};
  float mrun = -3.0e38f;
  float lrun = 0.f;
  const int qg_row = q0 + (w << 4) + lq;

  const int skey = tid >> 2;            // staging row 0..63
  const int schunk = (tid & 3) << 4;    // staging col base (16 elems)

  for (int t = 0; t <= qt; ++t) {
    const int k0 = t << 6;
    // stage K (rows=key, cols=d) and V (rows=d, cols=key; Vt is pre-transposed)
    {
      const unsigned short* kp = Kb + (size_t)(k0 + skey) * EMB + schunk;
      *(bf16x8*)&Ks[skey][schunk] = *(const bf16x8*)kp;
      *(bf16x8*)&Ks[skey][schunk + 8] = *(const bf16x8*)(kp + 8);
      const unsigned short* vp = Vb + (size_t)skey * TSEQ + k0 + schunk;
      *(bf16x8*)&Vs[skey][schunk] = *(const bf16x8*)vp;
      *(bf16x8*)&Vs[skey][schunk + 8] = *(const bf16x8*)(vp + 8);
    }
    __syncthreads();

    // S^T = K * Q^T : acc[mb] rows = key 16mb+4g+r, col = q lq
    f32x4 sacc[4];
#pragma unroll
    for (int mb = 0; mb < 4; ++mb) sacc[mb] = (f32x4){0.f, 0.f, 0.f, 0.f};
#pragma unroll
    for (int mb = 0; mb < 4; ++mb) {
      const bf16x8 ka0 = *(const bf16x8*)&Ks[(mb << 4) + lq][(g << 3)];
      const bf16x8 ka1 = *(const bf16x8*)&Ks[(mb << 4) + lq][(g << 3) + 32];
      sacc[mb] = __builtin_amdgcn_mfma_f32_16x16x32_bf16(ka0, qf0, sacc[mb], 0, 0, 0);
      sacc[mb] = __builtin_amdgcn_mfma_f32_16x16x32_bf16(ka1, qf1, sacc[mb], 0, 0, 0);
    }

    // online softmax (per q = lq; this lane holds 16 of 64 keys)
    const bool diag = (t == qt);
    float pv[16];
    float pm = -3.0e38f;
#pragma unroll
    for (int mb = 0; mb < 4; ++mb)
#pragma unroll
      for (int r = 0; r < 4; ++r) {
        float s = sacc[mb][r] * 0.125f;
        if (diag && (k0 + (mb << 4) + (g << 2) + r) > qg_row) s = -3.0e38f;
        pv[(mb << 2) + r] = s;
        pm = fmaxf(pm, s);
      }
    pm = fmaxf(pm, __shfl_xor(pm, 16, 64));
    pm = fmaxf(pm, __shfl_xor(pm, 32, 64));
    const float mnew = fmaxf(mrun, pm);
    const float corr = __expf(mrun - mnew);
    mrun = mnew;
    float ls = 0.f;
#pragma unroll
    for (int i = 0; i < 16; ++i) {
      const float p = __expf(pv[i] - mnew);
      pv[i] = p;
      ls += p;
    }
    ls += __shfl_xor(ls, 16, 64);
    ls += __shfl_xor(ls, 32, 64);
    lrun = lrun * corr + ls;

    // redistribute corr to the O-layout rows (q = 4g+r)
    float corr4[4];
#pragma unroll
    for (int r = 0; r < 4; ++r)
      corr4[r] = __shfl(corr, (lane & 48) | ((g << 2) + r), 64);
#pragma unroll
    for (int nb = 0; nb < 4; ++nb)
#pragma unroll
      for (int r = 0; r < 4; ++r) o[nb][r] *= corr4[r];

    // pack P (bf16) into per-wave LDS: Ps[w][q=lq][key]
    {
      unsigned int* pw = (unsigned int*)&Ps[w][lq][0];
#pragma unroll
      for (int mb = 0; mb < 4; ++mb) {
        const unsigned int u0 =
            (unsigned int)f2bf(pv[(mb << 2) + 0]) | ((unsigned int)f2bf(pv[(mb << 2) + 1]) << 16);
        const unsigned int u1 =
            (unsigned int)f2bf(pv[(mb << 2) + 2]) | ((unsigned int)f2bf(pv[(mb << 2) + 3]) << 16);
        pw[(mb << 3) + (g << 1) + 0] = u0;
        pw[(mb << 3) + (g << 1) + 1] = u1;
      }
    }
    // wave-private: only need our own writes visible to our own reads
    asm volatile("s_waitcnt lgkmcnt(0)" ::: "memory");

    // O += P * V  (A = P[q][key], B = V[key][d] via transposed Vs rows)
    {
      const bf16x8 pa0 = *(const bf16x8*)&Ps[w][lq][(g << 3)];
      const bf16x8 pa1 = *(const bf16x8*)&Ps[w][lq][(g << 3) + 32];
#pragma unroll
      for (int nb = 0; nb < 4; ++nb) {
        const bf16x8 v0 = *(const bf16x8*)&Vs[(nb << 4) + lq][(g << 3)];
        const bf16x8 v1 = *(const bf16x8*)&Vs[(nb << 4) + lq][(g << 3) + 32];
        o[nb] = __builtin_amdgcn_mfma_f32_16x16x32_bf16(pa0, v0, o[nb], 0, 0, 0);
        o[nb] = __builtin_amdgcn_mfma_f32_16x16x32_bf16(pa1, v1, o[nb], 0, 0, 0);
      }
    }
    __syncthreads();
  }

  // normalize + write: o[nb][r] = O[q=4g+r][d=16nb+lq]
  float li[4];
#pragma unroll
  for (int r = 0; r < 4; ++r)
    li[r] = 1.f / __shfl(lrun, (lane & 48) | ((g << 2) + r), 64);
#pragma unroll
  for (int nb = 0; nb < 4; ++nb)
#pragma unroll
    for (int r = 0; r < 4; ++r)
      Ob[(size_t)(q0 + (w << 4) + (g << 2) + r) * EMB + (nb << 4) + lq] =
          o[nb][r] * li[r];
}

// ---------------------------------------------------------------------------
extern "C" void kernel_launch(void* const* d_in, const int* in_sizes, int n_in,
                              void* d_out, int out_size, void* d_ws, size_t ws_size,
                              hipStream_t stream) {
  const float* x  = (const float*)d_in[0];
  const float* Wk = (const float*)d_in[1];
  const float* Wq = (const float*)d_in[2];
  const float* Wv = (const float*)d_in[3];
  const float* Wu = (const float*)d_in[4];
  const float* klnw = (const float*)d_in[5];
  const float* klnb = (const float*)d_in[6];
  const float* qlnw = (const float*)d_in[7];
  const float* qlnb = (const float*)d_in[8];
  float* out = (float*)d_out;

  char* wsb = (char*)d_ws;
  const size_t MB = 1024 * 1024;
  float* kbuf = (float*)(wsb);             // 32 MB fp32 k (dead after LN)
  float* qbuf = (float*)(wsb + 32 * MB);   // 32 MB fp32 q (dead after LN)
  unsigned short* vb16 = (unsigned short*)(wsb + 64 * MB);  // 16 MB bf16 v^T
  unsigned short* kb16 = (unsigned short*)(wsb + 80 * MB);  // 16 MB bf16 k
  unsigned short* qb16 = (unsigned short*)(wsb + 96 * MB);  // 16 MB bf16 q
  float* abuf = kbuf;  // attention output reuses kbuf region (32 MB)

  // 1) QKV projections: k,q fp32; v -> bf16 transposed [b*h][d][t]
  gemm_qkv_kernel<<<dim3(MROWS / 128, 24), 256, 0, stream>>>(
      x, Wk, Wq, Wv, kbuf, qbuf, vb16);

  // 2) per-head LayerNorm on q,k -> bf16
  {
    const int total_waves = 2 * MROWS * NHEAD;
    ln_kernel<<<total_waves / 4, 256, 0, stream>>>(qbuf, kbuf, qb16, kb16,
                                                   qlnw, qlnb, klnw, klnb);
  }

  // 3) bf16-MFMA causal flash attention -> abuf fp32 (t, e)
  attn_kernel<<<dim3(TSEQ / 64, NBATCH * NHEAD), 256, 0, stream>>>(
      qb16, kb16, vb16, abuf);

  // 4) output projection (fp32)
  gemm_out_kernel<<<dim3(MROWS / 128, EMB / 128), 256, 0, stream>>>(
      abuf, Wu, out);
}

// Round 5
// 459.395 us; speedup vs baseline: 4.3305x; 2.3188x over previous
//
#include <hip/hip_runtime.h>
#include <math.h>

#define EMB 1024
#define TSEQ 2048
#define NBATCH 4
#define NHEAD 16
#define HDIM 64
#define MROWS (NBATCH * TSEQ) /* 8192 */
#define KPAD 72

typedef __attribute__((ext_vector_type(8))) short bf16x8;
typedef __attribute__((ext_vector_type(4))) float f32x4;
typedef __attribute__((ext_vector_type(8))) unsigned short u16x8;
typedef __attribute__((ext_vector_type(4))) unsigned short u16x4;

typedef __attribute__((address_space(1))) const void gas_cv;
typedef __attribute__((address_space(3))) void las_v;

__device__ __forceinline__ void gload_lds16(const void* g, void* l) {
  __builtin_amdgcn_global_load_lds((gas_cv*)g, (las_v*)l, 16, 0, 0);
}

__device__ __forceinline__ unsigned short f2bf(float f) {
  unsigned int x = __float_as_uint(f);
  unsigned int r = x + 0x7fffu + ((x >> 16) & 1u);
  return (unsigned short)(r >> 16);
}
__device__ __forceinline__ float bf2f(unsigned short h) {
  return __uint_as_float((unsigned int)h << 16);
}

// ---------------------------------------------------------------------------
// Decompose fp32 tensors into bf16 hi/lo pairs. 12M elems total, 8 per thread.
// ---------------------------------------------------------------------------
__global__ __launch_bounds__(256) void decomp_kernel(
    const float* __restrict__ x, const float* __restrict__ Wk,
    const float* __restrict__ Wq, const float* __restrict__ Wv,
    const float* __restrict__ Wu,
    unsigned short* __restrict__ xh, unsigned short* __restrict__ xl,
    unsigned short* __restrict__ wkh, unsigned short* __restrict__ wkl,
    unsigned short* __restrict__ wqh, unsigned short* __restrict__ wql,
    unsigned short* __restrict__ wvh, unsigned short* __restrict__ wvl,
    unsigned short* __restrict__ wuh, unsigned short* __restrict__ wul) {
  const int v = blockIdx.x * blockDim.x + threadIdx.x;  // vec8 id
  const float* src;
  unsigned short *dh, *dl;
  size_t off;
  if (v < (1 << 20)) {
    src = x; dh = xh; dl = xl; off = (size_t)v << 3;
  } else {
    const int wv = v - (1 << 20);
    const int ws_ = wv >> 17;
    off = (size_t)(wv & 131071) << 3;
    if (ws_ == 0) { src = Wk; dh = wkh; dl = wkl; }
    else if (ws_ == 1) { src = Wq; dh = wqh; dl = wql; }
    else if (ws_ == 2) { src = Wv; dh = wvh; dl = wvl; }
    else { src = Wu; dh = wuh; dl = wul; }
  }
  const float4 f0 = *(const float4*)(src + off);
  const float4 f1 = *(const float4*)(src + off + 4);
  const float fv[8] = {f0.x, f0.y, f0.z, f0.w, f1.x, f1.y, f1.z, f1.w};
  u16x8 h, l;
#pragma unroll
  for (int i = 0; i < 8; ++i) {
    const unsigned short hb = f2bf(fv[i]);
    h[i] = hb;
    l[i] = f2bf(fv[i] - bf2f(hb));
  }
  *(u16x8*)(dh + off) = h;
  *(u16x8*)(dl + off) = l;
}

// ---------------------------------------------------------------------------
// Split-bf16 3-pass MFMA GEMM core: acc = A*B^T over logical K=1024, computed
// as hi*hi + hi*lo + lo*hi. Tile 128x128, BK=64, 256 threads (4 waves 2x2,
// each 64x64 = 4x4 frags of 16x16x32). global_load_lds(16B) staging with
// both-sides XOR swizzle: LDS linear, global source pre-swizzled, ds_read
// swizzled -> conflict-free b128 reads.
// ---------------------------------------------------------------------------
__device__ __forceinline__ void gemm3_core(
    const unsigned short* __restrict__ Ah, const unsigned short* __restrict__ Al,
    const unsigned short* __restrict__ Bh, const unsigned short* __restrict__ Bl,
    int bm, int bn, f32x4 acc[4][4]) {
  __shared__ __align__(16) unsigned short As[128][64];
  __shared__ __align__(16) unsigned short Bs[128][64];
  const int tid = threadIdx.x;
  const int lane = tid & 63;
  const int w = tid >> 6;
  const int lq = lane & 15;
  const int g = lane >> 4;
  const int wrO = (w >> 1) << 6;
  const int wcO = (w & 1) << 6;
  const int srow = (w << 5) + (lane >> 3);
  const int scbs = ((lane & 7) ^ (srow & 7)) << 3;  // pre-swizzled src col (elems)
  const int xsw = lq & 7;                           // read-side swizzle

  const size_t aoff0 = (size_t)(bm + srow) * EMB + scbs;
  const size_t boff0 = (size_t)(bn + srow) * EMB + scbs;

  for (int s = 0; s < 48; ++s) {
    const int p = s >> 4;
    const int kt = s & 15;
    const unsigned short* Asrc = (p < 2) ? Ah : Al;
    const unsigned short* Bsrc = (p == 1) ? Bl : Bh;
    const size_t ko = (size_t)(kt << 6);
    __syncthreads();  // previous compute done before overwrite
#pragma unroll
    for (int u = 0; u < 4; ++u) {
      gload_lds16(Asrc + aoff0 + ko + (size_t)(u << 3) * EMB,
                  &As[(w << 5) + (u << 3)][0]);
      gload_lds16(Bsrc + boff0 + ko + (size_t)(u << 3) * EMB,
                  &Bs[(w << 5) + (u << 3)][0]);
    }
    __syncthreads();  // vmcnt drained by compiler before barrier

    bf16x8 af[4][2], bf[4][2];
#pragma unroll
    for (int m = 0; m < 4; ++m)
#pragma unroll
      for (int kk = 0; kk < 2; ++kk) {
        af[m][kk] = *(const bf16x8*)&As[wrO + (m << 4) + lq]
                                      [(((kk << 2) + g) ^ xsw) << 3];
        bf[m][kk] = *(const bf16x8*)&Bs[wcO + (m << 4) + lq]
                                      [(((kk << 2) + g) ^ xsw) << 3];
      }
#pragma unroll
    for (int kk = 0; kk < 2; ++kk)
#pragma unroll
      for (int m = 0; m < 4; ++m)
#pragma unroll
        for (int nb = 0; nb < 4; ++nb)
          acc[m][nb] = __builtin_amdgcn_mfma_f32_16x16x32_bf16(
              af[m][kk], bf[nb][kk], acc[m][nb], 0, 0, 0);
  }
}

// ---------------------------------------------------------------------------
// QKV projections with fused per-head LayerNorm (k,q -> bf16) and transposed
// bf16 v. Grid (64, 24): blockIdx.y>>3 selects k/q/v.
// ---------------------------------------------------------------------------
__global__ __launch_bounds__(256, 2) void gemm3_qkv_kernel(
    const unsigned short* __restrict__ xh, const unsigned short* __restrict__ xl,
    const unsigned short* __restrict__ wkh, const unsigned short* __restrict__ wkl,
    const unsigned short* __restrict__ wqh, const unsigned short* __restrict__ wql,
    const unsigned short* __restrict__ wvh, const unsigned short* __restrict__ wvl,
    unsigned short* __restrict__ kb16, unsigned short* __restrict__ qb16,
    unsigned short* __restrict__ vb16,
    const float* __restrict__ klnw, const float* __restrict__ klnb,
    const float* __restrict__ qlnw, const float* __restrict__ qlnb) {
  const int sel = blockIdx.y >> 3;
  const int bm = blockIdx.x << 7;
  const int bn = (blockIdx.y & 7) << 7;
  const unsigned short* Bh = sel == 0 ? wkh : sel == 1 ? wqh : wvh;
  const unsigned short* Bl = sel == 0 ? wkl : sel == 1 ? wql : wvl;

  f32x4 acc[4][4];
#pragma unroll
  for (int m = 0; m < 4; ++m)
#pragma unroll
    for (int nb = 0; nb < 4; ++nb) acc[m][nb] = (f32x4){0.f, 0.f, 0.f, 0.f};

  gemm3_core(xh, xl, Bh, Bl, bm, bn, acc);

  const int lane = threadIdx.x & 63;
  const int w = threadIdx.x >> 6;
  const int lq = lane & 15;
  const int g = lane >> 4;
  const int wrO = (w >> 1) << 6;
  const int wcO = (w & 1) << 6;

  if (sel < 2) {
    // fused per-head LayerNorm: each wave's 64-col span is exactly one head
    unsigned short* C = sel == 0 ? kb16 : qb16;
    const float* lw = sel == 0 ? klnw : qlnw;
    const float* lb = sel == 0 ? klnb : qlnb;
    float wd[4], bd[4];
#pragma unroll
    for (int nb = 0; nb < 4; ++nb) {
      wd[nb] = lw[(nb << 4) + lq];
      bd[nb] = lb[(nb << 4) + lq];
    }
#pragma unroll
    for (int m = 0; m < 4; ++m) {
      const int r0 = bm + wrO + (m << 4) + (g << 2);
#pragma unroll
      for (int j = 0; j < 4; ++j) {
        float s = acc[m][0][j] + acc[m][1][j] + acc[m][2][j] + acc[m][3][j];
        s += __shfl_xor(s, 1, 64); s += __shfl_xor(s, 2, 64);
        s += __shfl_xor(s, 4, 64); s += __shfl_xor(s, 8, 64);
        const float mu = s * (1.f / 64.f);
        float v2 = 0.f;
#pragma unroll
        for (int nb = 0; nb < 4; ++nb) {
          const float d = acc[m][nb][j] - mu;
          v2 = fmaf(d, d, v2);
        }
        v2 += __shfl_xor(v2, 1, 64); v2 += __shfl_xor(v2, 2, 64);
        v2 += __shfl_xor(v2, 4, 64); v2 += __shfl_xor(v2, 8, 64);
        const float inv = rsqrtf(v2 * (1.f / 64.f) + 1e-5f);
#pragma unroll
        for (int nb = 0; nb < 4; ++nb) {
          const float val = (acc[m][nb][j] - mu) * inv * wd[nb] + bd[nb];
          C[(size_t)(r0 + j) * EMB + bn + wcO + (nb << 4) + lq] = f2bf(val);
        }
      }
    }
  } else {
    // v: bf16, transposed per head: vb16[((b*16+h)*64+d)*2048 + t]
#pragma unroll
    for (int m = 0; m < 4; ++m) {
      const int r0 = bm + wrO + (m << 4) + (g << 2);
      const int bb = r0 >> 11;
      const int tl = r0 & 2047;
#pragma unroll
      for (int nb = 0; nb < 4; ++nb) {
        const int n = bn + wcO + (nb << 4) + lq;
        const int hh = n >> 6;
        const int dd = n & 63;
        u16x4 pk;
#pragma unroll
        for (int j = 0; j < 4; ++j) pk[j] = f2bf(acc[m][nb][j]);
        *(u16x4*)(vb16 + ((((size_t)(bb << 4) + hh) << 6) + dd) * TSEQ + tl) = pk;
      }
    }
  }
}

// ---------------------------------------------------------------------------
// Output projection: A = attention out (hi/lo bf16), B = Wu (hi/lo), C fp32.
// ---------------------------------------------------------------------------
__global__ __launch_bounds__(256, 2) void gemm3_out_kernel(
    const unsigned short* __restrict__ ah, const unsigned short* __restrict__ al,
    const unsigned short* __restrict__ wuh, const unsigned short* __restrict__ wul,
    float* __restrict__ C) {
  const int bm = blockIdx.x << 7;
  const int bn = blockIdx.y << 7;
  f32x4 acc[4][4];
#pragma unroll
  for (int m = 0; m < 4; ++m)
#pragma unroll
    for (int nb = 0; nb < 4; ++nb) acc[m][nb] = (f32x4){0.f, 0.f, 0.f, 0.f};

  gemm3_core(ah, al, wuh, wul, bm, bn, acc);

  const int lane = threadIdx.x & 63;
  const int w = threadIdx.x >> 6;
  const int lq = lane & 15;
  const int g = lane >> 4;
  const int wrO = (w >> 1) << 6;
  const int wcO = (w & 1) << 6;
#pragma unroll
  for (int m = 0; m < 4; ++m) {
    const int r0 = bm + wrO + (m << 4) + (g << 2);
#pragma unroll
    for (int nb = 0; nb < 4; ++nb) {
      const int c = bn + wcO + (nb << 4) + lq;
#pragma unroll
      for (int j = 0; j < 4; ++j) C[(size_t)(r0 + j) * EMB + c] = acc[m][nb][j];
    }
  }
}

// ---------------------------------------------------------------------------
// bf16-MFMA causal flash attention (unchanged core from R2); epilogue now
// writes hi/lo bf16 for the split-precision output projection.
// ---------------------------------------------------------------------------
__global__ __launch_bounds__(256, 2) void attn_kernel(
    const unsigned short* __restrict__ Qg, const unsigned short* __restrict__ Kg,
    const unsigned short* __restrict__ Vt,
    unsigned short* __restrict__ Oh, unsigned short* __restrict__ Ol) {
  __shared__ __align__(16) unsigned short Ks[64][KPAD];
  __shared__ __align__(16) unsigned short Vs[64][KPAD];
  __shared__ __align__(16) unsigned short Ps[4][16][KPAD];
  const int tid = threadIdx.x;
  const int lane = tid & 63;
  const int w = tid >> 6;
  const int lq = lane & 15;
  const int g = lane >> 4;
  const int qt = (int)(gridDim.x - 1 - blockIdx.x);
  const int bh = blockIdx.y;
  const int bb = bh >> 4;
  const int hh = bh & 15;
  const int q0 = qt << 6;
  const unsigned short* Qb = Qg + ((size_t)bb * TSEQ) * EMB + hh * HDIM;
  const unsigned short* Kb = Kg + ((size_t)bb * TSEQ) * EMB + hh * HDIM;
  const unsigned short* Vb = Vt + (size_t)bh * HDIM * TSEQ;
  unsigned short* Ohb = Oh + ((size_t)bb * TSEQ) * EMB + hh * HDIM;
  unsigned short* Olb = Ol + ((size_t)bb * TSEQ) * EMB + hh * HDIM;

  bf16x8 qf0, qf1;
  {
    const unsigned short* qp = Qb + (size_t)(q0 + (w << 4) + lq) * EMB + (g << 3);
    qf0 = *(const bf16x8*)(qp);
    qf1 = *(const bf16x8*)(qp + 32);
  }

  f32x4 o[4];
#pragma unroll
  for (int nb = 0; nb < 4; ++nb) o[nb] = (f32x4){0.f, 0.f, 0.f, 0.f};
  float mrun = -3.0e38f;
  float lrun = 0.f;
  const int qg_row = q0 + (w << 4) + lq;

  const int skey = tid >> 2;
  const int schunk = (tid & 3) << 4;

  for (int t = 0; t <= qt; ++t) {
    const int k0 = t << 6;
    {
      const unsigned short* kp = Kb + (size_t)(k0 + skey) * EMB + schunk;
      *(bf16x8*)&Ks[skey][schunk] = *(const bf16x8*)kp;
      *(bf16x8*)&Ks[skey][schunk + 8] = *(const bf16x8*)(kp + 8);
      const unsigned short* vp = Vb + (size_t)skey * TSEQ + k0 + schunk;
      *(bf16x8*)&Vs[skey][schunk] = *(const bf16x8*)vp;
      *(bf16x8*)&Vs[skey][schunk + 8] = *(const bf16x8*)(vp + 8);
    }
    __syncthreads();

    f32x4 sacc[4];
#pragma unroll
    for (int mb = 0; mb < 4; ++mb) sacc[mb] = (f32x4){0.f, 0.f, 0.f, 0.f};
#pragma unroll
    for (int mb = 0; mb < 4; ++mb) {
      const bf16x8 ka0 = *(const bf16x8*)&Ks[(mb << 4) + lq][(g << 3)];
      const bf16x8 ka1 = *(const bf16x8*)&Ks[(mb << 4) + lq][(g << 3) + 32];
      sacc[mb] = __builtin_amdgcn_mfma_f32_16x16x32_bf16(ka0, qf0, sacc[mb], 0, 0, 0);
      sacc[mb] = __builtin_amdgcn_mfma_f32_16x16x32_bf16(ka1, qf1, sacc[mb], 0, 0, 0);
    }

    const bool diag = (t == qt);
    float pv[16];
    float pm = -3.0e38f;
#pragma unroll
    for (int mb = 0; mb < 4; ++mb)
#pragma unroll
      for (int r = 0; r < 4; ++r) {
        float s = sacc[mb][r] * 0.125f;
        if (diag && (k0 + (mb << 4) + (g << 2) + r) > qg_row) s = -3.0e38f;
        pv[(mb << 2) + r] = s;
        pm = fmaxf(pm, s);
      }
    pm = fmaxf(pm, __shfl_xor(pm, 16, 64));
    pm = fmaxf(pm, __shfl_xor(pm, 32, 64));
    const float mnew = fmaxf(mrun, pm);
    const float corr = __expf(mrun - mnew);
    mrun = mnew;
    float ls = 0.f;
#pragma unroll
    for (int i = 0; i < 16; ++i) {
      const float p = __expf(pv[i] - mnew);
      pv[i] = p;
      ls += p;
    }
    ls += __shfl_xor(ls, 16, 64);
    ls += __shfl_xor(ls, 32, 64);
    lrun = lrun * corr + ls;

    float corr4[4];
#pragma unroll
    for (int r = 0; r < 4; ++r)
      corr4[r] = __shfl(corr, (lane & 48) | ((g << 2) + r), 64);
#pragma unroll
    for (int nb = 0; nb < 4; ++nb)
#pragma unroll
      for (int r = 0; r < 4; ++r) o[nb][r] *= corr4[r];

    {
      unsigned int* pw = (unsigned int*)&Ps[w][lq][0];
#pragma unroll
      for (int mb = 0; mb < 4; ++mb) {
        const unsigned int u0 =
            (unsigned int)f2bf(pv[(mb << 2) + 0]) | ((unsigned int)f2bf(pv[(mb << 2) + 1]) << 16);
        const unsigned int u1 =
            (unsigned int)f2bf(pv[(mb << 2) + 2]) | ((unsigned int)f2bf(pv[(mb << 2) + 3]) << 16);
        pw[(mb << 3) + (g << 1) + 0] = u0;
        pw[(mb << 3) + (g << 1) + 1] = u1;
      }
    }
    asm volatile("s_waitcnt lgkmcnt(0)" ::: "memory");

    {
      const bf16x8 pa0 = *(const bf16x8*)&Ps[w][lq][(g << 3)];
      const bf16x8 pa1 = *(const bf16x8*)&Ps[w][lq][(g << 3) + 32];
#pragma unroll
      for (int nb = 0; nb < 4; ++nb) {
        const bf16x8 v0 = *(const bf16x8*)&Vs[(nb << 4) + lq][(g << 3)];
        const bf16x8 v1 = *(const bf16x8*)&Vs[(nb << 4) + lq][(g << 3) + 32];
        o[nb] = __builtin_amdgcn_mfma_f32_16x16x32_bf16(pa0, v0, o[nb], 0, 0, 0);
        o[nb] = __builtin_amdgcn_mfma_f32_16x16x32_bf16(pa1, v1, o[nb], 0, 0, 0);
      }
    }
    __syncthreads();
  }

  float li[4];
#pragma unroll
  for (int r = 0; r < 4; ++r)
    li[r] = 1.f / __shfl(lrun, (lane & 48) | ((g << 2) + r), 64);
#pragma unroll
  for (int nb = 0; nb < 4; ++nb)
#pragma unroll
    for (int r = 0; r < 4; ++r) {
      const float val = o[nb][r] * li[r];
      const unsigned short hb = f2bf(val);
      const size_t idx =
          (size_t)(q0 + (w << 4) + (g << 2) + r) * EMB + (nb << 4) + lq;
      Ohb[idx] = hb;
      Olb[idx] = f2bf(val - bf2f(hb));
    }
}

// ---------------------------------------------------------------------------
extern "C" void kernel_launch(void* const* d_in, const int* in_sizes, int n_in,
                              void* d_out, int out_size, void* d_ws, size_t ws_size,
                              hipStream_t stream) {
  const float* x  = (const float*)d_in[0];
  const float* Wk = (const float*)d_in[1];
  const float* Wq = (const float*)d_in[2];
  const float* Wv = (const float*)d_in[3];
  const float* Wu = (const float*)d_in[4];
  const float* klnw = (const float*)d_in[5];
  const float* klnb = (const float*)d_in[6];
  const float* qlnw = (const float*)d_in[7];
  const float* qlnb = (const float*)d_in[8];
  float* out = (float*)d_out;

  char* wsb = (char*)d_ws;
  const size_t MB = 1024 * 1024;
  unsigned short* ah   = (unsigned short*)(wsb + 0 * MB);    // attn out hi (16MB)
  unsigned short* al   = (unsigned short*)(wsb + 16 * MB);   // attn out lo (16MB)
  unsigned short* kb16 = (unsigned short*)(wsb + 32 * MB);
  unsigned short* qb16 = (unsigned short*)(wsb + 48 * MB);
  unsigned short* xh   = (unsigned short*)(wsb + 64 * MB);
  unsigned short* xl   = (unsigned short*)(wsb + 80 * MB);
  unsigned short* vb16 = (unsigned short*)(wsb + 96 * MB);
  unsigned short* wkh  = (unsigned short*)(wsb + 112 * MB);
  unsigned short* wkl  = (unsigned short*)(wsb + 114 * MB);
  unsigned short* wqh  = (unsigned short*)(wsb + 116 * MB);
  unsigned short* wql  = (unsigned short*)(wsb + 118 * MB);
  unsigned short* wvh  = (unsigned short*)(wsb + 120 * MB);
  unsigned short* wvl  = (unsigned short*)(wsb + 122 * MB);
  unsigned short* wuh  = (unsigned short*)(wsb + 124 * MB);
  unsigned short* wul  = (unsigned short*)(wsb + 126 * MB);

  // 1) hi/lo decomposition of x and all weights
  decomp_kernel<<<6144, 256, 0, stream>>>(x, Wk, Wq, Wv, Wu, xh, xl, wkh, wkl,
                                          wqh, wql, wvh, wvl, wuh, wul);

  // 2) QKV projections (split-bf16 MFMA) + fused per-head LN; v -> bf16^T
  gemm3_qkv_kernel<<<dim3(MROWS / 128, 24), 256, 0, stream>>>(
      xh, xl, wkh, wkl, wqh, wql, wvh, wvl, kb16, qb16, vb16,
      klnw, klnb, qlnw, qlnb);

  // 3) bf16-MFMA causal flash attention -> hi/lo bf16
  attn_kernel<<<dim3(TSEQ / 64, NBATCH * NHEAD), 256, 0, stream>>>(
      qb16, kb16, vb16, ah, al);

  // 4) output projection (split-bf16 MFMA) -> fp32 out
  gemm3_out_kernel<<<dim3(MROWS / 128, EMB / 128), 256, 0, stream>>>(
      ah, al, wuh, wul, out);
}